// Round 1
// baseline (310.093 us; speedup 1.0000x reference)
//
#include <hip/hip_runtime.h>
#include <stdint.h>

// BasicAttention: B=4, C=256, IC=128, N=4096, fp32 in/out.
// k1: W -> bf16.  k2: q/k/v projections via MFMA (q,k as [b][n][128], v as [b][c][n], all bf16 in ws).
// k3: flash attention (online softmax), MFMA 16x16x32 bf16, epilogue gamma*O/l + 2x.
// ws: q 4MB | k 4MB | v 8MB | wbf 256KB  (~16.5MB)

#define Bn 4
#define Cn 256
#define ICn 128
#define Nn 4096

typedef __attribute__((ext_vector_type(8))) short bf16x8;
typedef __attribute__((ext_vector_type(4))) float f32x4;

__device__ __forceinline__ unsigned short f2bf(float f) {
  union { float f; uint32_t u; } v; v.f = f;
  uint32_t r = (v.u + 0x7fffu + ((v.u >> 16) & 1u)) >> 16;
  return (unsigned short)r;
}

__global__ __launch_bounds__(256) void cvt_weights(const float* __restrict__ Wq,
                                                   const float* __restrict__ Wk,
                                                   const float* __restrict__ Wv,
                                                   unsigned short* __restrict__ wbf) {
  int i4 = blockIdx.x * 256 + threadIdx.x;  // 0..32767, 4 floats each (Wq 8192, Wk 8192, Wv 16384)
  float4 f;
  if (i4 < 8192)       f = ((const float4*)Wq)[i4];
  else if (i4 < 16384) f = ((const float4*)Wk)[i4 - 8192];
  else                 f = ((const float4*)Wv)[i4 - 16384];
  ushort4 o;
  o.x = f2bf(f.x); o.y = f2bf(f.y); o.z = f2bf(f.z); o.w = f2bf(f.w);
  ((ushort4*)wbf)[i4] = o;
}

// wbf layout: [0,32768) Wq rows, [32768,65536) Wk rows, [65536,131072) Wv rows; row-major [o][c].
__global__ __launch_bounds__(256) void proj_kernel(const float* __restrict__ x,
                                                   const unsigned short* __restrict__ wbf,
                                                   const float* __restrict__ bq,
                                                   const float* __restrict__ bk,
                                                   const float* __restrict__ bv,
                                                   unsigned short* __restrict__ q,
                                                   unsigned short* __restrict__ k,
                                                   unsigned short* __restrict__ v) {
  const int b = blockIdx.y;
  const int n0 = blockIdx.x * 64;
  const int tid = threadIdx.x;
  const int lane = tid & 63;
  const int w = tid >> 6;
  const int c0 = lane & 15, g = lane >> 4;

  // x tile transposed: [px][c] bf16; row stride 264*2=528B (16B multiple, ~bank-balanced)
  __shared__ __align__(16) unsigned short xT[64][264];

  #pragma unroll
  for (int t = 0; t < 16; ++t) {
    int c = tid;       // c fastest across lanes -> conflict-free LDS writes; global reads L1-hit across t
    int px = t * 4;
    float4 f4 = *(const float4*)(x + ((size_t)(b * Cn + c)) * Nn + n0 + px);
    xT[px + 0][c] = f2bf(f4.x);
    xT[px + 1][c] = f2bf(f4.y);
    xT[px + 2][c] = f2bf(f4.z);
    xT[px + 3][c] = f2bf(f4.w);
  }
  __syncthreads();

  // A-frags: A[m=lane&15][kc=(lane>>4)*8+j], wave w owns pixels w*16..w*16+15
  bf16x8 a[8];
  #pragma unroll
  for (int kk = 0; kk < 8; ++kk)
    a[kk] = *(const bf16x8*)&xT[w * 16 + c0][kk * 32 + g * 8];

  #pragma unroll
  for (int ot = 0; ot < 32; ++ot) {   // 0..7 q, 8..15 k, 16..31 v
    int woff, bcol;
    if (ot < 8)       { bcol = ot * 16 + c0;        woff = 0     + bcol * Cn; }
    else if (ot < 16) { bcol = (ot - 8) * 16 + c0;  woff = 32768 + bcol * Cn; }
    else              { bcol = (ot - 16) * 16 + c0; woff = 65536 + bcol * Cn; }
    f32x4 acc = {0.f, 0.f, 0.f, 0.f};
    #pragma unroll
    for (int kk = 0; kk < 8; ++kk) {
      bf16x8 bf = *(const bf16x8*)(wbf + woff + kk * 32 + g * 8);  // B[kc][o]=W[o][c], c contiguous
      acc = __builtin_amdgcn_mfma_f32_16x16x32_bf16(a[kk], bf, acc, 0, 0, 0);
    }
    float bias = (ot < 8) ? bq[bcol] : (ot < 16 ? bk[bcol] : bv[bcol]);
    #pragma unroll
    for (int r = 0; r < 4; ++r) {     // C/D: col=lane&15 (=out channel), row=g*4+r (=pixel)
      int n = n0 + w * 16 + g * 4 + r;
      unsigned short val = f2bf(acc[r] + bias);
      if (ot < 8)       q[((size_t)b * Nn + n) * ICn + bcol] = val;
      else if (ot < 16) k[((size_t)b * Nn + n) * ICn + bcol] = val;
      else              v[((size_t)b * Cn + bcol) * Nn + n] = val;  // v kept c-major for attn staging
    }
  }
}

__global__ __launch_bounds__(256) void attn_kernel(const unsigned short* __restrict__ q,
                                                   const unsigned short* __restrict__ k,
                                                   const unsigned short* __restrict__ v,
                                                   const float* __restrict__ x,
                                                   const float* __restrict__ gamma,
                                                   float* __restrict__ out) {
  const int b = blockIdx.y;
  const int n0 = blockIdx.x * 64;      // 64 query rows per block, wave w owns rows w*16..+15
  const int tid = threadIdx.x;
  const int lane = tid & 63;
  const int w = tid >> 6;
  const int c0 = lane & 15, g = lane >> 4;

  __shared__ __align__(16) union SM {
    struct {
      unsigned short ks[64][136];    // K tile [j][i], stride 272B
      unsigned short vs[256][72];    // V tile [c][j], stride 144B
      unsigned short ps[4][16][72];  // per-wave P [row][j]
    } a;                             // 63488 B
    float os[64][129];               // epilogue staging, half of C at a time (stride==1 mod 32 banks)
  } sm;

  bf16x8 aq[4];                      // Q A-frags, persistent: rows n0+w*16+(lane&15), K-dim=128
  #pragma unroll
  for (int kk = 0; kk < 4; ++kk)
    aq[kk] = *(const bf16x8*)(q + ((size_t)b * Nn + n0 + w * 16 + c0) * ICn + kk * 32 + g * 8);

  f32x4 zero = {0.f, 0.f, 0.f, 0.f};
  f32x4 oacc[16];                    // O [16 rows][256 c] in C-layout, 16 col-tiles
  #pragma unroll
  for (int i = 0; i < 16; ++i) oacc[i] = zero;
  float mrow[4], lrow[4];
  #pragma unroll
  for (int r = 0; r < 4; ++r) { mrow[r] = -1e30f; lrow[r] = 0.f; }
  const float scale = 0.08838834764831845f;  // 1/sqrt(128)

  for (int j0 = 0; j0 < Nn; j0 += 64) {
    __syncthreads();
    #pragma unroll
    for (int t = 0; t < 4; ++t) {    // stage K: 64 rows x 128, 1024 uint4
      int idx = tid + t * 256;
      int rr = idx >> 4, i8 = idx & 15;
      *(uint4*)&sm.a.ks[rr][i8 * 8] =
          *(const uint4*)(k + ((size_t)b * Nn + j0 + rr) * ICn + i8 * 8);
    }
    #pragma unroll
    for (int t = 0; t < 8; ++t) {    // stage V: 256 rows(c) x 64(j), 2048 uint4
      int idx = tid + t * 256;
      int cc = idx >> 3, j8 = idx & 7;
      *(uint4*)&sm.a.vs[cc][j8 * 8] =
          *(const uint4*)(v + ((size_t)b * Cn + cc) * Nn + j0 + j8 * 8);
    }
    __syncthreads();

    // S[n][j] = sum_i q[n][i]*k[j][i] : B-frag = ks[jt*16+(lane&15)][kc], contiguous 16B
    f32x4 s[4];
    #pragma unroll
    for (int jt = 0; jt < 4; ++jt) {
      f32x4 acc = zero;
      #pragma unroll
      for (int kk = 0; kk < 4; ++kk) {
        bf16x8 bfr = *(const bf16x8*)&sm.a.ks[jt * 16 + c0][kk * 32 + g * 8];
        acc = __builtin_amdgcn_mfma_f32_16x16x32_bf16(aq[kk], bfr, acc, 0, 0, 0);
      }
      s[jt] = acc * scale;
    }

    // online softmax: rows live in reg r (row = g*4+r); cols spread over the 16-lane c0 group
    float rm[4];
    #pragma unroll
    for (int r = 0; r < 4; ++r)
      rm[r] = fmaxf(fmaxf(s[0][r], s[1][r]), fmaxf(s[2][r], s[3][r]));
    #pragma unroll
    for (int d = 1; d < 16; d <<= 1) {
      #pragma unroll
      for (int r = 0; r < 4; ++r)
        rm[r] = fmaxf(rm[r], __shfl_xor(rm[r], d, 64));
    }

    float mnew[4];
    int changed = 0;
    #pragma unroll
    for (int r = 0; r < 4; ++r) {
      mnew[r] = fmaxf(mrow[r], rm[r]);
      changed |= (mnew[r] > mrow[r]) ? 1 : 0;
    }

    float p[4][4], rs[4];
    #pragma unroll
    for (int jt = 0; jt < 4; ++jt) {
      #pragma unroll
      for (int r = 0; r < 4; ++r)
        p[jt][r] = __expf(s[jt][r] - mnew[r]);
    }
    #pragma unroll
    for (int r = 0; r < 4; ++r)
      rs[r] = (p[0][r] + p[1][r]) + (p[2][r] + p[3][r]);
    #pragma unroll
    for (int d = 1; d < 16; d <<= 1) {
      #pragma unroll
      for (int r = 0; r < 4; ++r)
        rs[r] += __shfl_xor(rs[r], d, 64);
    }

    if (__any(changed)) {            // wave-uniform; m stabilizes fast for small energies
      float alpha[4];
      #pragma unroll
      for (int r = 0; r < 4; ++r) {
        alpha[r] = __expf(mrow[r] - mnew[r]);
        mrow[r] = mnew[r];
        lrow[r] = alpha[r] * lrow[r] + rs[r];
      }
      #pragma unroll
      for (int i = 0; i < 16; ++i) {
        oacc[i][0] *= alpha[0]; oacc[i][1] *= alpha[1];
        oacc[i][2] *= alpha[2]; oacc[i][3] *= alpha[3];
      }
    } else {
      #pragma unroll
      for (int r = 0; r < 4; ++r) lrow[r] += rs[r];
    }

    // P: C-layout -> LDS -> A-layout (wave-private region; no barrier needed)
    #pragma unroll
    for (int jt = 0; jt < 4; ++jt) {
      #pragma unroll
      for (int r = 0; r < 4; ++r)
        sm.a.ps[w][g * 4 + r][jt * 16 + c0] = f2bf(p[jt][r]);
    }

    // O[n][c] += P[n][j] * v[c][j] : B-frag = vs[ct*16+(lane&15)][kj], contiguous 16B
    #pragma unroll
    for (int ks2 = 0; ks2 < 2; ++ks2) {
      bf16x8 pa = *(const bf16x8*)&sm.a.ps[w][c0][ks2 * 32 + g * 8];
      #pragma unroll
      for (int ct = 0; ct < 16; ++ct) {
        bf16x8 vb = *(const bf16x8*)&sm.a.vs[ct * 16 + c0][ks2 * 32 + g * 8];
        oacc[ct] = __builtin_amdgcn_mfma_f32_16x16x32_bf16(pa, vb, oacc[ct], 0, 0, 0);
      }
    }
  }

  const float gm = gamma[0];
  float gl[4];
  #pragma unroll
  for (int r = 0; r < 4; ++r) gl[r] = gm / lrow[r];

  // epilogue: stage (gamma/l)*O through LDS so the global store is coalesced over n
  #pragma unroll
  for (int half = 0; half < 2; ++half) {
    __syncthreads();
    #pragma unroll
    for (int ct = 0; ct < 8; ++ct) {
      f32x4 oa = oacc[half * 8 + ct];
      #pragma unroll
      for (int r = 0; r < 4; ++r)
        sm.os[w * 16 + g * 4 + r][ct * 16 + c0] = oa[r] * gl[r];
    }
    __syncthreads();
    for (int t = 0; t < 32; ++t) {
      int cl = (tid >> 6) + t * 4;   // 0..127
      int px = tid & 63;
      int cg = half * 128 + cl;
      size_t off = ((size_t)(b * Cn + cg)) * Nn + n0 + px;
      out[off] = sm.os[px][cl] + 2.0f * x[off];
    }
  }
}

extern "C" void kernel_launch(void* const* d_in, const int* in_sizes, int n_in,
                              void* d_out, int out_size, void* d_ws, size_t ws_size,
                              hipStream_t stream) {
  const float* x     = (const float*)d_in[0];
  const float* Wq    = (const float*)d_in[1];
  const float* bq    = (const float*)d_in[2];
  const float* Wk    = (const float*)d_in[3];
  const float* bk    = (const float*)d_in[4];
  const float* Wv    = (const float*)d_in[5];
  const float* bv    = (const float*)d_in[6];
  const float* gamma = (const float*)d_in[7];
  float* out = (float*)d_out;

  unsigned short* qws = (unsigned short*)d_ws;              // [4][4096][128] bf16
  unsigned short* kws = qws + (size_t)Bn * Nn * ICn;        // [4][4096][128] bf16
  unsigned short* vws = kws + (size_t)Bn * Nn * ICn;        // [4][256][4096] bf16
  unsigned short* wbf = vws + (size_t)Bn * Cn * Nn;         // 131072 bf16

  hipLaunchKernelGGL(cvt_weights, dim3(128), dim3(256), 0, stream, Wq, Wk, Wv, wbf);
  hipLaunchKernelGGL(proj_kernel, dim3(64, 4), dim3(256), 0, stream,
                     x, wbf, bq, bk, bv, qws, kws, vws);
  hipLaunchKernelGGL(attn_kernel, dim3(64, 4), dim3(256), 0, stream,
                     qws, kws, vws, x, gamma, out);
}

// Round 2
// 286.730 us; speedup vs baseline: 1.0815x; 1.0815x over previous
//
#include <hip/hip_runtime.h>
#include <stdint.h>

// BasicAttention: B=4, C=256, IC=128, N=4096, fp32 in/out.
// k1: W -> bf16.
// k2: projections via MFMA. q,k: operand-swapped (A=W, B=x^T) so lanes hold 4 consecutive
//     out-channels -> ushort4 stores to [n][128] layout (q pre-scaled by 1/sqrt(128)).
//     v: original orientation (lanes hold 4 consecutive pixels) -> ushort4 stores to [c][n].
// k3: flash attention, 512-thread blocks = 4 q-subtiles x 2 key-splits, in-LDS (m,l,O) combine.
//     K/V LDS tiles XOR-swizzled (16B-chunk ^ row) for bank uniformity, no padding.
// ws: q 4MB | k 4MB | v 8MB | wbf 256KB  (~16.5MB)

#define Bn 4
#define Cn 256
#define ICn 128
#define Nn 4096

typedef __attribute__((ext_vector_type(8))) short bf16x8;
typedef __attribute__((ext_vector_type(4))) float f32x4;

__device__ __forceinline__ unsigned short f2bf(float f) {
  union { float f; uint32_t u; } v; v.f = f;
  uint32_t r = (v.u + 0x7fffu + ((v.u >> 16) & 1u)) >> 16;
  return (unsigned short)r;
}

__global__ __launch_bounds__(256) void cvt_weights(const float* __restrict__ Wq,
                                                   const float* __restrict__ Wk,
                                                   const float* __restrict__ Wv,
                                                   unsigned short* __restrict__ wbf) {
  int i4 = blockIdx.x * 256 + threadIdx.x;  // 0..32767, 4 floats each
  float4 f;
  if (i4 < 8192)       f = ((const float4*)Wq)[i4];
  else if (i4 < 16384) f = ((const float4*)Wk)[i4 - 8192];
  else                 f = ((const float4*)Wv)[i4 - 16384];
  ushort4 o;
  o.x = f2bf(f.x); o.y = f2bf(f.y); o.z = f2bf(f.z); o.w = f2bf(f.w);
  ((ushort4*)wbf)[i4] = o;
}

// wbf: [0,32768) Wq, [32768,65536) Wk, [65536,131072) Wv; row-major [o][c].
__global__ __launch_bounds__(256) void proj_kernel(const float* __restrict__ x,
                                                   const unsigned short* __restrict__ wbf,
                                                   const float* __restrict__ bq,
                                                   const float* __restrict__ bk,
                                                   const float* __restrict__ bv,
                                                   unsigned short* __restrict__ q,
                                                   unsigned short* __restrict__ k,
                                                   unsigned short* __restrict__ v) {
  const int b = blockIdx.y;
  const int n0 = blockIdx.x * 64;
  const int tid = threadIdx.x;
  const int lane = tid & 63;
  const int w = tid >> 6;
  const int c0 = lane & 15, g = lane >> 4;

  __shared__ __align__(16) unsigned short xT[64][264];  // [px][c]

  #pragma unroll
  for (int t = 0; t < 16; ++t) {
    int c = tid;
    int px = t * 4;
    float4 f4 = *(const float4*)(x + ((size_t)(b * Cn + c)) * Nn + n0 + px);
    xT[px + 0][c] = f2bf(f4.x);
    xT[px + 1][c] = f2bf(f4.y);
    xT[px + 2][c] = f2bf(f4.z);
    xT[px + 3][c] = f2bf(f4.w);
  }
  __syncthreads();

  // x frags: serve as A (m=pixel) for v, and as B (n=pixel) for q/k (layouts coincide).
  bf16x8 a[8];
  #pragma unroll
  for (int kk = 0; kk < 8; ++kk)
    a[kk] = *(const bf16x8*)&xT[w * 16 + c0][kk * 32 + g * 8];

  f32x4 zero = {0.f, 0.f, 0.f, 0.f};
  const float scale = 0.08838834764831845f;  // 1/sqrt(128), folded into q

  // ---- q (8 tiles) and k (8 tiles): A = W rows (m=out_ch), B = x^T (n=pixel)
  #pragma unroll
  for (int ot = 0; ot < 16; ++ot) {
    const int isq = (ot < 8);
    const int otl = isq ? ot : (ot - 8);
    const unsigned short* wp = wbf + (isq ? 0 : 32768) + ((size_t)(otl * 16 + c0)) * Cn;
    f32x4 acc = zero;
    #pragma unroll
    for (int kk = 0; kk < 8; ++kk) {
      bf16x8 wf = *(const bf16x8*)(wp + kk * 32 + g * 8);
      acc = __builtin_amdgcn_mfma_f32_16x16x32_bf16(wf, a[kk], acc, 0, 0, 0);
    }
    // D: row = out_ch = otl*16 + g*4 + r, col = pixel = w*16 + c0
    ushort4 st;
    const int chb = otl * 16 + g * 4;
    if (isq) {
      st.x = f2bf((acc[0] + bq[chb + 0]) * scale);
      st.y = f2bf((acc[1] + bq[chb + 1]) * scale);
      st.z = f2bf((acc[2] + bq[chb + 2]) * scale);
      st.w = f2bf((acc[3] + bq[chb + 3]) * scale);
      *(ushort4*)(q + ((size_t)(b * Nn + n0 + w * 16 + c0)) * ICn + chb) = st;
    } else {
      st.x = f2bf(acc[0] + bk[chb + 0]);
      st.y = f2bf(acc[1] + bk[chb + 1]);
      st.z = f2bf(acc[2] + bk[chb + 2]);
      st.w = f2bf(acc[3] + bk[chb + 3]);
      *(ushort4*)(k + ((size_t)(b * Nn + n0 + w * 16 + c0)) * ICn + chb) = st;
    }
  }

  // ---- v (16 tiles): A = x (m=pixel), B = W^T (n=out_ch); lanes hold 4 consecutive pixels
  #pragma unroll
  for (int ot = 0; ot < 16; ++ot) {
    const int bcol = ot * 16 + c0;
    const unsigned short* wp = wbf + 65536 + ((size_t)bcol) * Cn;
    f32x4 acc = zero;
    #pragma unroll
    for (int kk = 0; kk < 8; ++kk) {
      bf16x8 wf = *(const bf16x8*)(wp + kk * 32 + g * 8);
      acc = __builtin_amdgcn_mfma_f32_16x16x32_bf16(a[kk], wf, acc, 0, 0, 0);
    }
    const float bias = bv[bcol];
    ushort4 st;
    st.x = f2bf(acc[0] + bias);
    st.y = f2bf(acc[1] + bias);
    st.z = f2bf(acc[2] + bias);
    st.w = f2bf(acc[3] + bias);
    *(ushort4*)(v + ((size_t)(b * Cn + bcol)) * Nn + n0 + w * 16 + g * 4) = st;
  }
}

// 512 threads: wave w = qg + 4*ksplit? -> w = tid>>6; qg = w&3 (16 q-rows), ksplit = w>>2 (key half)
__global__ __launch_bounds__(512) void attn_kernel(const unsigned short* __restrict__ q,
                                                   const unsigned short* __restrict__ k,
                                                   const unsigned short* __restrict__ v,
                                                   const float* __restrict__ x,
                                                   const float* __restrict__ gamma,
                                                   float* __restrict__ out) {
  const int b = blockIdx.y;
  const int n0 = blockIdx.x * 64;
  const int tid = threadIdx.x;
  const int lane = tid & 63;
  const int w = tid >> 6;        // 0..7
  const int qg = w & 3;          // q sub-tile (16 rows)
  const int ksplit = w >> 2;     // 0/1: key half of each 64-key tile
  const int c0 = lane & 15, g = lane >> 4;

  // XOR-swizzled tiles: phys 16B-chunk = logical chunk ^ (row & mask)
  __shared__ __align__(16) union SM {
    struct {
      unsigned short ks[64][128];   // K tile [key][ch], 16 chunks/row, swizzle mask 15  (16384B)
      unsigned short vs[256][64];   // V tile [ch][key],  8 chunks/row, swizzle mask 7   (32768B)
      unsigned short ps[8][16][40]; // per-wave P [row][32 keys + pad]                   (10240B)
    } a;                            // 59392B
    float os[64][129];              // epilogue staging (half of C at a time)            (33024B)
  } sm;
  __shared__ float ml[8][16][2];    // per-wave per-row (m, l) for the split-K combine

  bf16x8 aq[4];                     // Q frags: rows n0 + qg*16 + c0 (pre-scaled)
  #pragma unroll
  for (int kk = 0; kk < 4; ++kk)
    aq[kk] = *(const bf16x8*)(q + ((size_t)(b * Nn + n0 + qg * 16 + c0)) * ICn + kk * 32 + g * 8);

  f32x4 zero = {0.f, 0.f, 0.f, 0.f};
  f32x4 oacc[16];
  #pragma unroll
  for (int i = 0; i < 16; ++i) oacc[i] = zero;
  float mrow[4], lrow[4];
  #pragma unroll
  for (int r = 0; r < 4; ++r) { mrow[r] = -1e30f; lrow[r] = 0.f; }

  for (int j0 = 0; j0 < Nn; j0 += 64) {
    __syncthreads();
    #pragma unroll
    for (int t = 0; t < 2; ++t) {   // K: 64 rows x 16 uint4
      int idx = tid + t * 512;
      int rr = idx >> 4, ch = idx & 15;
      int pch = ch ^ (rr & 15);
      *(uint4*)&sm.a.ks[rr][pch * 8] =
          *(const uint4*)(k + ((size_t)(b * Nn + j0 + rr)) * ICn + ch * 8);
    }
    #pragma unroll
    for (int t = 0; t < 4; ++t) {   // V: 256 rows x 8 uint4
      int idx = tid + t * 512;
      int cc = idx >> 3, ch = idx & 7;
      int pch = ch ^ (cc & 7);
      *(uint4*)&sm.a.vs[cc][pch * 8] =
          *(const uint4*)(v + ((size_t)(b * Cn + cc)) * Nn + j0 + ch * 8);
    }
    __syncthreads();

    // S (pre-scaled): wave's 32 keys = ksplit*32 + jt*16 + c0
    f32x4 s[2];
    #pragma unroll
    for (int jt = 0; jt < 2; ++jt) {
      int krow = ksplit * 32 + jt * 16 + c0;   // krow & 15 == c0
      f32x4 acc = zero;
      #pragma unroll
      for (int kk = 0; kk < 4; ++kk) {
        int pc = (kk * 4 + g) ^ c0;
        bf16x8 bfr = *(const bf16x8*)&sm.a.ks[krow][pc * 8];
        acc = __builtin_amdgcn_mfma_f32_16x16x32_bf16(aq[kk], bfr, acc, 0, 0, 0);
      }
      s[jt] = acc;
    }

    // online softmax over this wave's 32 keys (rows = g*4+r, cols spread over c0 group)
    float rm[4];
    #pragma unroll
    for (int r = 0; r < 4; ++r) rm[r] = fmaxf(s[0][r], s[1][r]);
    #pragma unroll
    for (int d = 1; d < 16; d <<= 1) {
      #pragma unroll
      for (int r = 0; r < 4; ++r) rm[r] = fmaxf(rm[r], __shfl_xor(rm[r], d, 64));
    }

    float mnew[4];
    int changed = 0;
    #pragma unroll
    for (int r = 0; r < 4; ++r) {
      mnew[r] = fmaxf(mrow[r], rm[r]);
      changed |= (mnew[r] > mrow[r]) ? 1 : 0;
    }

    float p[2][4], rs[4];
    #pragma unroll
    for (int jt = 0; jt < 2; ++jt)
      #pragma unroll
      for (int r = 0; r < 4; ++r)
        p[jt][r] = __expf(s[jt][r] - mnew[r]);
    #pragma unroll
    for (int r = 0; r < 4; ++r) rs[r] = p[0][r] + p[1][r];
    #pragma unroll
    for (int d = 1; d < 16; d <<= 1) {
      #pragma unroll
      for (int r = 0; r < 4; ++r) rs[r] += __shfl_xor(rs[r], d, 64);
    }

    if (__any(changed)) {
      float alpha[4];
      #pragma unroll
      for (int r = 0; r < 4; ++r) {
        alpha[r] = __expf(mrow[r] - mnew[r]);
        mrow[r] = mnew[r];
        lrow[r] = alpha[r] * lrow[r] + rs[r];
      }
      #pragma unroll
      for (int i = 0; i < 16; ++i) {
        oacc[i][0] *= alpha[0]; oacc[i][1] *= alpha[1];
        oacc[i][2] *= alpha[2]; oacc[i][3] *= alpha[3];
      }
    } else {
      #pragma unroll
      for (int r = 0; r < 4; ++r) lrow[r] += rs[r];
    }

    // P: C-layout -> wave-private LDS -> A-layout
    #pragma unroll
    for (int jt = 0; jt < 2; ++jt)
      #pragma unroll
      for (int r = 0; r < 4; ++r)
        sm.a.ps[w][g * 4 + r][jt * 16 + c0] = f2bf(p[jt][r]);

    // O += P(16x32) * V(256x32)^T over wave's key half
    bf16x8 pa = *(const bf16x8*)&sm.a.ps[w][c0][g * 8];
    #pragma unroll
    for (int ct = 0; ct < 16; ++ct) {
      int vrow = ct * 16 + c0;
      int pc = (ksplit * 4 + g) ^ (c0 & 7);
      bf16x8 vb = *(const bf16x8*)&sm.a.vs[vrow][pc * 8];
      oacc[ct] = __builtin_amdgcn_mfma_f32_16x16x32_bf16(pa, vb, oacc[ct], 0, 0, 0);
    }
  }

  // ---- split-K combine across wave pairs (w and w^4), then epilogue
  if (c0 == 0) {
    #pragma unroll
    for (int r = 0; r < 4; ++r) {
      ml[w][g * 4 + r][0] = mrow[r];
      ml[w][g * 4 + r][1] = lrow[r];
    }
  }
  __syncthreads();                 // ml visible; all K/V/P LDS reads complete

  const float gm = gamma[0];
  const int partner = w ^ 4;
  float coef[4];
  #pragma unroll
  for (int r = 0; r < 4; ++r) {
    float mo = ml[partner][g * 4 + r][0];
    float lo = ml[partner][g * 4 + r][1];
    float mt = fmaxf(mrow[r], mo);
    float es = __expf(mrow[r] - mt);
    float eo = __expf(mo - mt);
    float lt = es * lrow[r] + eo * lo;
    coef[r] = gm * es / lt;
  }

  #pragma unroll
  for (int half = 0; half < 2; ++half) {
    if (half) __syncthreads();     // previous half's os reads complete
    if (ksplit == 0) {
      #pragma unroll
      for (int ct = 0; ct < 8; ++ct) {
        f32x4 oa = oacc[half * 8 + ct];
        #pragma unroll
        for (int r = 0; r < 4; ++r)
          sm.os[qg * 16 + g * 4 + r][ct * 16 + c0] = oa[r] * coef[r];
      }
    }
    __syncthreads();
    if (ksplit == 1) {
      #pragma unroll
      for (int ct = 0; ct < 8; ++ct) {
        f32x4 oa = oacc[half * 8 + ct];
        #pragma unroll
        for (int r = 0; r < 4; ++r)
          sm.os[qg * 16 + g * 4 + r][ct * 16 + c0] += oa[r] * coef[r];
      }
    }
    __syncthreads();
    for (int t = 0; t < 16; ++t) {
      int cl = (tid >> 6) + t * 8;     // 0..127
      int px = tid & 63;
      int cg = half * 128 + cl;
      size_t off = ((size_t)(b * Cn + cg)) * Nn + n0 + px;
      out[off] = sm.os[px][cl] + 2.0f * x[off];
    }
  }
}

extern "C" void kernel_launch(void* const* d_in, const int* in_sizes, int n_in,
                              void* d_out, int out_size, void* d_ws, size_t ws_size,
                              hipStream_t stream) {
  const float* x     = (const float*)d_in[0];
  const float* Wq    = (const float*)d_in[1];
  const float* bq    = (const float*)d_in[2];
  const float* Wk    = (const float*)d_in[3];
  const float* bk    = (const float*)d_in[4];
  const float* Wv    = (const float*)d_in[5];
  const float* bv    = (const float*)d_in[6];
  const float* gamma = (const float*)d_in[7];
  float* out = (float*)d_out;

  unsigned short* qws = (unsigned short*)d_ws;              // [4][4096][128] bf16 (pre-scaled)
  unsigned short* kws = qws + (size_t)Bn * Nn * ICn;        // [4][4096][128] bf16
  unsigned short* vws = kws + (size_t)Bn * Nn * ICn;        // [4][256][4096] bf16
  unsigned short* wbf = vws + (size_t)Bn * Cn * Nn;         // 131072 bf16

  hipLaunchKernelGGL(cvt_weights, dim3(128), dim3(256), 0, stream, Wq, Wk, Wv, wbf);
  hipLaunchKernelGGL(proj_kernel, dim3(64, 4), dim3(256), 0, stream,
                     x, wbf, bq, bk, bv, qws, kws, vws);
  hipLaunchKernelGGL(attn_kernel, dim3(64, 4), dim3(512), 0, stream,
                     qws, kws, vws, x, gamma, out);
}